// Round 1
// baseline (42298.447 us; speedup 1.0000x reference)
//
#include <hip/hip_runtime.h>
#include <cstdint>
#include <cstddef>

#define DIM 256
#define SLOPE 0.2f

// ---- monotonic float<->uint encoding for atomicMax on floats ----
__device__ __forceinline__ unsigned enc_f(float f) {
  unsigned u = __float_as_uint(f);
  return (u & 0x80000000u) ? ~u : (u | 0x80000000u);
}
__device__ __forceinline__ float dec_f(unsigned u) {
  u = (u & 0x80000000u) ? (u ^ 0x80000000u) : ~u;
  return __uint_as_float(u);
}

// out[i] = bias[i % 256], vectorized float4
__global__ void init_out_kernel(float4* __restrict__ out4, const float4* __restrict__ bias4,
                                int total4) {
  int i = blockIdx.x * blockDim.x + threadIdx.x;
  if (i < total4) out4[i] = bias4[i & 63];
}

// Wh[r0..r0+31][*] = H[r0..r0+31][*] @ W ; 256 threads, thread t owns column t.
__global__ void gemm_kernel(const float* __restrict__ H, const float* __restrict__ W,
                            float* __restrict__ Wh, int N) {
  __shared__ float Hs[32][DIM];
  const int r0 = blockIdx.x * 32;
  const int t = threadIdx.x;
#pragma unroll
  for (int i = 0; i < 32; ++i) {
    int r = r0 + i;
    Hs[i][t] = (r < N) ? H[(size_t)r * DIM + t] : 0.f;
  }
  __syncthreads();
  float acc[32];
#pragma unroll
  for (int i = 0; i < 32; ++i) acc[i] = 0.f;
#pragma unroll 4
  for (int k = 0; k < DIM; ++k) {
    float w = W[k * DIM + t];  // coalesced; W is 256KB -> L2-resident
#pragma unroll
    for (int i = 0; i < 32; ++i) acc[i] += Hs[i][k] * w;  // Hs broadcast: no bank conflict
  }
#pragma unroll
  for (int i = 0; i < 32; ++i) {
    int r = r0 + i;
    if (r < N) Wh[(size_t)r * DIM + t] = acc[i];
  }
}

// one wave per node: s_dst[n] = Wh[n].a[:256], s_src[n] = Wh[n].a[256:]; init emax/esum
__global__ void node_scores_kernel(const float* __restrict__ Wh, const float* __restrict__ a,
                                   float* __restrict__ s_dst, float* __restrict__ s_src,
                                   unsigned* __restrict__ emax, float* __restrict__ esum, int N) {
  int wid = (blockIdx.x * blockDim.x + threadIdx.x) >> 6;
  int lane = threadIdx.x & 63;
  if (wid >= N) return;
  float d = 0.f, s = 0.f;
#pragma unroll
  for (int j = 0; j < 4; ++j) {
    int c = lane + 64 * j;
    float v = Wh[(size_t)wid * DIM + c];
    d += v * a[c];
    s += v * a[DIM + c];
  }
#pragma unroll
  for (int off = 32; off > 0; off >>= 1) {
    d += __shfl_down(d, off);
    s += __shfl_down(s, off);
  }
  if (lane == 0) {
    s_dst[wid] = d;
    s_src[wid] = s;
    emax[wid] = enc_f(-__builtin_inff());
    esum[wid] = 0.f;
  }
}

__device__ __forceinline__ float edge_logit(const int* row, const int* col,
                                            const float* s_dst, const float* s_src, int e,
                                            int& r) {
  r = row[e];
  float v = s_dst[r] + s_src[col[e]];
  return v > 0.f ? v : SLOPE * v;
}

__global__ void edge_max_kernel(const int* __restrict__ row, const int* __restrict__ col,
                                const float* __restrict__ s_dst, const float* __restrict__ s_src,
                                unsigned* __restrict__ emax, int E) {
  int e = blockIdx.x * blockDim.x + threadIdx.x;
  if (e >= E) return;
  int r;
  float v = edge_logit(row, col, s_dst, s_src, e, r);
  atomicMax(&emax[r], enc_f(v));
}

__global__ void edge_sum_kernel(const int* __restrict__ row, const int* __restrict__ col,
                                const float* __restrict__ s_dst, const float* __restrict__ s_src,
                                const unsigned* __restrict__ emax, float* __restrict__ esum,
                                int E) {
  int e = blockIdx.x * blockDim.x + threadIdx.x;
  if (e >= E) return;
  int r;
  float v = edge_logit(row, col, s_dst, s_src, e, r);
  atomicAdd(&esum[r], __expf(v - dec_f(emax[r])));
}

// one wave per edge: out[row] += alpha * Wh[col]
__global__ void edge_aggregate_kernel(const int* __restrict__ row, const int* __restrict__ col,
                                      const float* __restrict__ s_dst,
                                      const float* __restrict__ s_src,
                                      const unsigned* __restrict__ emax,
                                      const float* __restrict__ esum,
                                      const float* __restrict__ Wh, float* __restrict__ out,
                                      int E) {
  int wid = (int)((blockIdx.x * (unsigned)blockDim.x + threadIdx.x) >> 6);
  if (wid >= E) return;
  int lane = threadIdx.x & 63;
  int r = row[wid];
  int c = col[wid];
  float v = s_dst[r] + s_src[c];
  v = v > 0.f ? v : SLOPE * v;
  float alpha = __expf(v - dec_f(emax[r])) / fmaxf(esum[r], 1e-12f);
  float4 w4 = ((const float4*)(Wh + (size_t)c * DIM))[lane];
  float* o = out + (size_t)r * DIM + lane * 4;
  atomicAdd(o + 0, alpha * w4.x);
  atomicAdd(o + 1, alpha * w4.y);
  atomicAdd(o + 2, alpha * w4.z);
  atomicAdd(o + 3, alpha * w4.w);
}

extern "C" void kernel_launch(void* const* d_in, const int* in_sizes, int n_in,
                              void* d_out, int out_size, void* d_ws, size_t ws_size,
                              hipStream_t stream) {
  const float* H = (const float*)d_in[0];
  const float* W[3] = {(const float*)d_in[1], (const float*)d_in[2], (const float*)d_in[3]};
  const float* a[3] = {(const float*)d_in[4], (const float*)d_in[5], (const float*)d_in[6]};
  const float* bias = (const float*)d_in[7];
  const int* row[3] = {(const int*)d_in[8], (const int*)d_in[10], (const int*)d_in[12]};
  const int* col[3] = {(const int*)d_in[9], (const int*)d_in[11], (const int*)d_in[13]};
  const int N = in_sizes[0] / DIM;
  const int E = in_sizes[8];
  float* out = (float*)d_out;

  // workspace layout
  char* ws = (char*)d_ws;
  float* Wh = (float*)ws;                                   // N*DIM floats (102.4 MB)
  float* s_dst = (float*)(ws + (size_t)N * DIM * sizeof(float));
  float* s_src = s_dst + N;
  unsigned* emax = (unsigned*)(s_src + N);
  float* esum = (float*)(emax + N);

  // out = bias broadcast
  {
    int total4 = N * (DIM / 4);
    init_out_kernel<<<(total4 + 255) / 256, 256, 0, stream>>>((float4*)out, (const float4*)bias,
                                                              total4);
  }

  for (int t = 0; t < 3; ++t) {
    gemm_kernel<<<(N + 31) / 32, 256, 0, stream>>>(H, W[t], Wh, N);
    node_scores_kernel<<<(N * 64 + 255) / 256, 256, 0, stream>>>(Wh, a[t], s_dst, s_src, emax,
                                                                 esum, N);
    edge_max_kernel<<<(E + 255) / 256, 256, 0, stream>>>(row[t], col[t], s_dst, s_src, emax, E);
    edge_sum_kernel<<<(E + 255) / 256, 256, 0, stream>>>(row[t], col[t], s_dst, s_src, emax, esum,
                                                         E);
    edge_aggregate_kernel<<<(E * 64 + 255) / 256, 256, 0, stream>>>(row[t], col[t], s_dst, s_src,
                                                                    emax, esum, Wh, out, E);
  }
  (void)n_in;
  (void)out_size;
  (void)ws_size;
}

// Round 2
// 12776.838 us; speedup vs baseline: 3.3106x; 3.3106x over previous
//
#include <hip/hip_runtime.h>
#include <cstdint>
#include <cstddef>

#define DIM 256
#define SLOPE 0.2f

// out[i] = bias[i % 256], vectorized float4
__global__ void init_out_kernel(float4* __restrict__ out4, const float4* __restrict__ bias4,
                                int total4) {
  int i = blockIdx.x * blockDim.x + threadIdx.x;
  if (i < total4) out4[i] = bias4[i & 63];
}

// Wh[r0..r0+31][*] = H[r0..r0+31][*] @ W ; 256 threads, thread t owns column t.
__global__ void gemm_kernel(const float* __restrict__ H, const float* __restrict__ W,
                            float* __restrict__ Wh, int N) {
  __shared__ float Hs[32][DIM];
  const int r0 = blockIdx.x * 32;
  const int t = threadIdx.x;
#pragma unroll
  for (int i = 0; i < 32; ++i) {
    int r = r0 + i;
    Hs[i][t] = (r < N) ? H[(size_t)r * DIM + t] : 0.f;
  }
  __syncthreads();
  float acc[32];
#pragma unroll
  for (int i = 0; i < 32; ++i) acc[i] = 0.f;
#pragma unroll 4
  for (int k = 0; k < DIM; ++k) {
    float w = W[k * DIM + t];  // coalesced; W is 256KB -> L2-resident
#pragma unroll
    for (int i = 0; i < 32; ++i) acc[i] += Hs[i][k] * w;  // Hs broadcast: no bank conflict
  }
#pragma unroll
  for (int i = 0; i < 32; ++i) {
    int r = r0 + i;
    if (r < N) Wh[(size_t)r * DIM + t] = acc[i];
  }
}

// one wave per node: s_dst[n] = Wh[n].a[:256], s_src[n] = Wh[n].a[256:]
__global__ void node_scores_kernel(const float* __restrict__ Wh, const float* __restrict__ a,
                                   float* __restrict__ s_dst, float* __restrict__ s_src, int N) {
  int wid = (blockIdx.x * blockDim.x + threadIdx.x) >> 6;
  int lane = threadIdx.x & 63;
  if (wid >= N) return;
  float d = 0.f, s = 0.f;
#pragma unroll
  for (int j = 0; j < 4; ++j) {
    int c = lane + 64 * j;
    float v = Wh[(size_t)wid * DIM + c];
    d += v * a[c];
    s += v * a[DIM + c];
  }
#pragma unroll
  for (int off = 32; off > 0; off >>= 1) {
    d += __shfl_down(d, off);
    s += __shfl_down(s, off);
  }
  if (lane == 0) {
    s_dst[wid] = d;
    s_src[wid] = s;
  }
}

// --- CSR build: count -> scan -> scatter ---
__global__ void csr_count_kernel(const int* __restrict__ row, int* __restrict__ counts, int E) {
  int e = blockIdx.x * blockDim.x + threadIdx.x;
  if (e < E) atomicAdd(&counts[row[e]], 1);
}

// single block of 1024 threads: exclusive scan of counts[N] -> row_ptr[N+1], cursor[N]
__global__ void csr_scan_kernel(const int* __restrict__ counts, int* __restrict__ row_ptr,
                                int* __restrict__ cursor, int N) {
  __shared__ int part[1024];
  const int t = threadIdx.x;
  const int chunk = (N + 1023) / 1024;
  const int lo = t * chunk;
  const int hi = min(lo + chunk, N);
  int s = 0;
  for (int i = lo; i < hi; ++i) s += counts[i];
  part[t] = s;
  __syncthreads();
  // inclusive Hillis-Steele scan over part[]
  for (int off = 1; off < 1024; off <<= 1) {
    int u = (t >= off) ? part[t - off] : 0;
    __syncthreads();
    part[t] += u;
    __syncthreads();
  }
  int running = part[t] - s;  // exclusive base for this chunk
  for (int i = lo; i < hi; ++i) {
    row_ptr[i] = running;
    cursor[i] = running;
    running += counts[i];
  }
  if (t == 1023) row_ptr[N] = part[1023];
}

__global__ void csr_scatter_kernel(const int* __restrict__ row, const int* __restrict__ col,
                                   int* __restrict__ cursor, int* __restrict__ col_csr, int E) {
  int e = blockIdx.x * blockDim.x + threadIdx.x;
  if (e >= E) return;
  int pos = atomicAdd(&cursor[row[e]], 1);
  col_csr[pos] = col[e];
}

// one wave per destination node: fused segment-max + softmax-weighted aggregation.
// out[n] += (sum_e exp(v_e - m) * Wh[col_e]) / (sum_e exp(v_e - m))
__global__ void gat_node_kernel(const int* __restrict__ row_ptr, const int* __restrict__ col_csr,
                                const float* __restrict__ s_dst, const float* __restrict__ s_src,
                                const float* __restrict__ Wh, float* __restrict__ out, int N) {
  int n = (int)((blockIdx.x * (unsigned)blockDim.x + threadIdx.x) >> 6);
  if (n >= N) return;
  int lane = threadIdx.x & 63;
  int beg = row_ptr[n], end = row_ptr[n + 1];
  if (beg == end) return;  // empty segment: reference contributes 0
  float sd = s_dst[n];
  // pass 1: segment max, lane-parallel over edges
  float m = -__builtin_inff();
  for (int p = beg + lane; p < end; p += 64) {
    float v = sd + s_src[col_csr[p]];
    v = v > 0.f ? v : SLOPE * v;
    m = fmaxf(m, v);
  }
#pragma unroll
  for (int off = 32; off > 0; off >>= 1) m = fmaxf(m, __shfl_down(m, off));
  m = __shfl(m, 0);
  // pass 2: wave-cooperative per edge; each lane owns 4 output columns
  float4 acc = {0.f, 0.f, 0.f, 0.f};
  float sum = 0.f;
  for (int p = beg; p < end; ++p) {
    int c = col_csr[p];
    float v = sd + s_src[c];
    v = v > 0.f ? v : SLOPE * v;
    float pe = __expf(v - m);
    sum += pe;
    float4 w = ((const float4*)(Wh + (size_t)c * DIM))[lane];
    acc.x += pe * w.x;
    acc.y += pe * w.y;
    acc.z += pe * w.z;
    acc.w += pe * w.w;
  }
  float inv = 1.f / fmaxf(sum, 1e-12f);
  float4* o = (float4*)(out + (size_t)n * DIM) + lane;
  float4 cur = *o;
  cur.x += acc.x * inv;
  cur.y += acc.y * inv;
  cur.z += acc.z * inv;
  cur.w += acc.w * inv;
  *o = cur;
}

extern "C" void kernel_launch(void* const* d_in, const int* in_sizes, int n_in,
                              void* d_out, int out_size, void* d_ws, size_t ws_size,
                              hipStream_t stream) {
  const float* H = (const float*)d_in[0];
  const float* W[3] = {(const float*)d_in[1], (const float*)d_in[2], (const float*)d_in[3]};
  const float* a[3] = {(const float*)d_in[4], (const float*)d_in[5], (const float*)d_in[6]};
  const float* bias = (const float*)d_in[7];
  const int* row[3] = {(const int*)d_in[8], (const int*)d_in[10], (const int*)d_in[12]};
  const int* col[3] = {(const int*)d_in[9], (const int*)d_in[11], (const int*)d_in[13]};
  const int N = in_sizes[0] / DIM;
  const int E = in_sizes[8];
  float* out = (float*)d_out;

  // workspace layout (~117 MB)
  char* ws = (char*)d_ws;
  size_t off = 0;
  float* Wh = (float*)(ws + off);       off += (size_t)N * DIM * sizeof(float);
  float* s_dst = (float*)(ws + off);    off += (size_t)N * sizeof(float);
  float* s_src = (float*)(ws + off);    off += (size_t)N * sizeof(float);
  int* counts = (int*)(ws + off);       off += (size_t)N * sizeof(int);   // reused as cursor
  int* row_ptr = (int*)(ws + off);      off += (size_t)(N + 1) * sizeof(int);
  int* col_csr = (int*)(ws + off);      off += (size_t)E * sizeof(int);

  // out = bias broadcast
  {
    int total4 = N * (DIM / 4);
    init_out_kernel<<<(total4 + 255) / 256, 256, 0, stream>>>((float4*)out, (const float4*)bias,
                                                              total4);
  }

  const int eblocks = (E + 255) / 256;
  for (int t = 0; t < 3; ++t) {
    gemm_kernel<<<(N + 31) / 32, 256, 0, stream>>>(H, W[t], Wh, N);
    node_scores_kernel<<<(N * 64 + 255) / 256, 256, 0, stream>>>(Wh, a[t], s_dst, s_src, N);
    hipMemsetAsync(counts, 0, (size_t)N * sizeof(int), stream);
    csr_count_kernel<<<eblocks, 256, 0, stream>>>(row[t], counts, E);
    csr_scan_kernel<<<1, 1024, 0, stream>>>(counts, row_ptr, counts /*cursor*/, N);
    csr_scatter_kernel<<<eblocks, 256, 0, stream>>>(row[t], col[t], counts, col_csr, E);
    gat_node_kernel<<<(N * 64 + 255) / 256, 256, 0, stream>>>(row_ptr, col_csr, s_dst, s_src, Wh,
                                                              out, N);
  }
  (void)n_in;
  (void)out_size;
  (void)ws_size;
}

// Round 3
// 4051.915 us; speedup vs baseline: 10.4391x; 3.1533x over previous
//
#include <hip/hip_runtime.h>
#include <cstdint>
#include <cstddef>

#define DIM 256
#define SLOPE 0.2f
#define KC 32

// out[i] = bias[i % 256], vectorized float4
__global__ void init_out_kernel(float4* __restrict__ out4, const float4* __restrict__ bias4,
                                int total4) {
  int i = blockIdx.x * blockDim.x + threadIdx.x;
  if (i < total4) out4[i] = bias4[i & 63];
}

// Wh = H @ W. 64x64 tile / block (256 thr), 4x4 micro-tile / thread, K chunks of 32 in LDS.
// A staged transposed (Ast[k][row], stride 68 keeps float4 rows 16B-aligned).
__global__ __launch_bounds__(256, 2) void gemm_kernel(const float* __restrict__ H,
                                                      const float* __restrict__ W,
                                                      float* __restrict__ Wh, int N) {
  __shared__ float Ast[KC][68];  // [k][row0..63], padded
  __shared__ float Bs[KC][64];   // [k][col0..63]
  const int t = threadIdx.x;
  const int r0 = blockIdx.x * 64;
  const int c0 = blockIdx.y * 64;
  const int tx = t & 15;   // col group: cols c0 + tx*4 .. +3
  const int ty = t >> 4;   // row group: rows r0 + ty*4 .. +3
  float4 acc0 = {0, 0, 0, 0}, acc1 = {0, 0, 0, 0}, acc2 = {0, 0, 0, 0}, acc3 = {0, 0, 0, 0};

  for (int k0 = 0; k0 < DIM; k0 += KC) {
#pragma unroll
    for (int j = 0; j < 2; ++j) {  // stage A (64 rows x 32 k) transposed
      int idx = t + j * 256;       // 0..511 float4s
      int row = idx >> 3;
      int kq = idx & 7;
      int r = r0 + row;
      float4 h = (r < N) ? *(const float4*)&H[(size_t)r * DIM + k0 + kq * 4]
                         : make_float4(0.f, 0.f, 0.f, 0.f);
      Ast[kq * 4 + 0][row] = h.x;
      Ast[kq * 4 + 1][row] = h.y;
      Ast[kq * 4 + 2][row] = h.z;
      Ast[kq * 4 + 3][row] = h.w;
    }
#pragma unroll
    for (int j = 0; j < 2; ++j) {  // stage B (32 k x 64 cols)
      int idx = t + j * 256;
      int krow = idx >> 4;
      int cq = idx & 15;
      *(float4*)&Bs[krow][cq * 4] = *(const float4*)&W[(size_t)(k0 + krow) * DIM + c0 + cq * 4];
    }
    __syncthreads();
#pragma unroll
    for (int k = 0; k < KC; ++k) {
      float4 a4 = *(const float4*)&Ast[k][ty * 4];  // 4 rows at this k
      float4 b4 = *(const float4*)&Bs[k][tx * 4];   // 4 cols at this k
      acc0.x += a4.x * b4.x; acc0.y += a4.x * b4.y; acc0.z += a4.x * b4.z; acc0.w += a4.x * b4.w;
      acc1.x += a4.y * b4.x; acc1.y += a4.y * b4.y; acc1.z += a4.y * b4.z; acc1.w += a4.y * b4.w;
      acc2.x += a4.z * b4.x; acc2.y += a4.z * b4.y; acc2.z += a4.z * b4.z; acc2.w += a4.z * b4.w;
      acc3.x += a4.w * b4.x; acc3.y += a4.w * b4.y; acc3.z += a4.w * b4.z; acc3.w += a4.w * b4.w;
    }
    __syncthreads();
  }
  const int rbase = r0 + ty * 4;
  const size_t cb = c0 + tx * 4;
  if (rbase + 0 < N) *(float4*)&Wh[(size_t)(rbase + 0) * DIM + cb] = acc0;
  if (rbase + 1 < N) *(float4*)&Wh[(size_t)(rbase + 1) * DIM + cb] = acc1;
  if (rbase + 2 < N) *(float4*)&Wh[(size_t)(rbase + 2) * DIM + cb] = acc2;
  if (rbase + 3 < N) *(float4*)&Wh[(size_t)(rbase + 3) * DIM + cb] = acc3;
}

// one wave per node: s_dst[n] = Wh[n].a[:256], s_src[n] = Wh[n].a[256:]
__global__ void node_scores_kernel(const float* __restrict__ Wh, const float* __restrict__ a,
                                   float* __restrict__ s_dst, float* __restrict__ s_src, int N) {
  int wid = (blockIdx.x * blockDim.x + threadIdx.x) >> 6;
  int lane = threadIdx.x & 63;
  if (wid >= N) return;
  float d = 0.f, s = 0.f;
#pragma unroll
  for (int j = 0; j < 4; ++j) {
    int c = lane + 64 * j;
    float v = Wh[(size_t)wid * DIM + c];
    d += v * a[c];
    s += v * a[DIM + c];
  }
#pragma unroll
  for (int off = 32; off > 0; off >>= 1) {
    d += __shfl_down(d, off);
    s += __shfl_down(s, off);
  }
  if (lane == 0) {
    s_dst[wid] = d;
    s_src[wid] = s;
  }
}

// --- CSR build: count -> scan -> scatter ---
__global__ void csr_count_kernel(const int* __restrict__ row, int* __restrict__ counts, int E) {
  int e = blockIdx.x * blockDim.x + threadIdx.x;
  if (e < E) atomicAdd(&counts[row[e]], 1);
}

// single block of 1024 threads: exclusive scan of counts[N] -> row_ptr[N+1], cursor[N]
__global__ void csr_scan_kernel(const int* __restrict__ counts, int* __restrict__ row_ptr,
                                int* __restrict__ cursor, int N) {
  __shared__ int part[1024];
  const int t = threadIdx.x;
  const int chunk = (N + 1023) / 1024;
  const int lo = t * chunk;
  const int hi = min(lo + chunk, N);
  int s = 0;
  for (int i = lo; i < hi; ++i) s += counts[i];
  part[t] = s;
  __syncthreads();
  for (int off = 1; off < 1024; off <<= 1) {
    int u = (t >= off) ? part[t - off] : 0;
    __syncthreads();
    part[t] += u;
    __syncthreads();
  }
  int running = part[t] - s;  // exclusive base for this chunk
  for (int i = lo; i < hi; ++i) {
    row_ptr[i] = running;
    cursor[i] = running;
    running += counts[i];
  }
  if (t == 1023) row_ptr[N] = part[1023];
}

__global__ void csr_scatter_kernel(const int* __restrict__ row, const int* __restrict__ col,
                                   int* __restrict__ cursor, int* __restrict__ col_csr, int E) {
  int e = blockIdx.x * blockDim.x + threadIdx.x;
  if (e >= E) return;
  int pos = atomicAdd(&cursor[row[e]], 1);
  col_csr[pos] = col[e];
}

// one wave per destination node: fused segment-max + softmax-weighted aggregation.
__global__ void gat_node_kernel(const int* __restrict__ row_ptr, const int* __restrict__ col_csr,
                                const float* __restrict__ s_dst, const float* __restrict__ s_src,
                                const float* __restrict__ Wh, float* __restrict__ out, int N) {
  int n = (int)((blockIdx.x * (unsigned)blockDim.x + threadIdx.x) >> 6);
  if (n >= N) return;
  int lane = threadIdx.x & 63;
  int beg = row_ptr[n], end = row_ptr[n + 1];
  if (beg == end) return;
  float sd = s_dst[n];
  float m = -__builtin_inff();
  for (int p = beg + lane; p < end; p += 64) {
    float v = sd + s_src[col_csr[p]];
    v = v > 0.f ? v : SLOPE * v;
    m = fmaxf(m, v);
  }
#pragma unroll
  for (int off = 32; off > 0; off >>= 1) m = fmaxf(m, __shfl_down(m, off));
  m = __shfl(m, 0);
  float4 acc = {0.f, 0.f, 0.f, 0.f};
  float sum = 0.f;
  for (int p = beg; p < end; ++p) {
    int c = col_csr[p];
    float v = sd + s_src[c];
    v = v > 0.f ? v : SLOPE * v;
    float pe = __expf(v - m);
    sum += pe;
    float4 w = ((const float4*)(Wh + (size_t)c * DIM))[lane];
    acc.x += pe * w.x;
    acc.y += pe * w.y;
    acc.z += pe * w.z;
    acc.w += pe * w.w;
  }
  float inv = 1.f / fmaxf(sum, 1e-12f);
  float4* o = (float4*)(out + (size_t)n * DIM) + lane;
  float4 cur = *o;
  cur.x += acc.x * inv;
  cur.y += acc.y * inv;
  cur.z += acc.z * inv;
  cur.w += acc.w * inv;
  *o = cur;
}

extern "C" void kernel_launch(void* const* d_in, const int* in_sizes, int n_in,
                              void* d_out, int out_size, void* d_ws, size_t ws_size,
                              hipStream_t stream) {
  const float* H = (const float*)d_in[0];
  const float* W[3] = {(const float*)d_in[1], (const float*)d_in[2], (const float*)d_in[3]};
  const float* a[3] = {(const float*)d_in[4], (const float*)d_in[5], (const float*)d_in[6]};
  const float* bias = (const float*)d_in[7];
  const int* row[3] = {(const int*)d_in[8], (const int*)d_in[10], (const int*)d_in[12]};
  const int* col[3] = {(const int*)d_in[9], (const int*)d_in[11], (const int*)d_in[13]};
  const int N = in_sizes[0] / DIM;
  const int E = in_sizes[8];
  float* out = (float*)d_out;

  char* ws = (char*)d_ws;
  size_t off = 0;
  float* Wh = (float*)(ws + off);    off += (size_t)N * DIM * sizeof(float);
  float* s_dst = (float*)(ws + off); off += (size_t)N * sizeof(float);
  float* s_src = (float*)(ws + off); off += (size_t)N * sizeof(float);
  int* counts = (int*)(ws + off);    off += (size_t)N * sizeof(int);  // reused as cursor
  int* row_ptr = (int*)(ws + off);   off += (size_t)(N + 1) * sizeof(int);
  int* col_csr = (int*)(ws + off);   off += (size_t)E * sizeof(int);

  {
    int total4 = N * (DIM / 4);
    init_out_kernel<<<(total4 + 255) / 256, 256, 0, stream>>>((float4*)out, (const float4*)bias,
                                                              total4);
  }

  const int eblocks = (E + 255) / 256;
  dim3 ggrid((N + 63) / 64, DIM / 64);
  for (int t = 0; t < 3; ++t) {
    gemm_kernel<<<ggrid, 256, 0, stream>>>(H, W[t], Wh, N);
    node_scores_kernel<<<(N * 64 + 255) / 256, 256, 0, stream>>>(Wh, a[t], s_dst, s_src, N);
    hipMemsetAsync(counts, 0, (size_t)N * sizeof(int), stream);
    csr_count_kernel<<<eblocks, 256, 0, stream>>>(row[t], counts, E);
    csr_scan_kernel<<<1, 1024, 0, stream>>>(counts, row_ptr, counts /*cursor*/, N);
    csr_scatter_kernel<<<eblocks, 256, 0, stream>>>(row[t], col[t], counts, col_csr, E);
    gat_node_kernel<<<(N * 64 + 255) / 256, 256, 0, stream>>>(row_ptr, col_csr, s_dst, s_src, Wh,
                                                              out, N);
  }
  (void)n_in;
  (void)out_size;
  (void)ws_size;
}

// Round 4
// 3179.886 us; speedup vs baseline: 13.3019x; 1.2742x over previous
//
#include <hip/hip_runtime.h>
#include <cstdint>
#include <cstddef>

#define DIM 256
#define SLOPE 0.2f

typedef __attribute__((ext_vector_type(8))) short short8;  // 8 bf16 (4 VGPRs)
typedef __attribute__((ext_vector_type(4))) float f32x4;   // 4 fp32 acc

__device__ __forceinline__ unsigned short f2bf(float f) {  // RNE fp32->bf16
  unsigned u = __float_as_uint(f);
  u += 0x7fffu + ((u >> 16) & 1u);
  return (unsigned short)(u >> 16);
}
__device__ __forceinline__ float bf2f(unsigned short h) {
  return __uint_as_float(((unsigned)h) << 16);
}

// Wt[t][n][k] = bf16(W_t[k][n]) ; grid (256, 3), 256 threads
__global__ void wtrans_kernel(const float* __restrict__ W0, const float* __restrict__ W1,
                              const float* __restrict__ W2, unsigned short* __restrict__ Wt) {
  const float* W = blockIdx.y == 0 ? W0 : (blockIdx.y == 1 ? W1 : W2);
  int k = blockIdx.x, n = threadIdx.x;
  Wt[((size_t)blockIdx.y * DIM + n) * DIM + k] = f2bf(W[k * DIM + n]);
}

// 64-row tile / block (256 thr = 4 waves). Whole K=256 staged in LDS as bf16.
// Wave w computes rows w*16..+15 x all 256 cols via 16x16x32 bf16 MFMA.
// Epilogue: s_dst/s_src from fp32 accs (shuffle reduce) + bf16 Wh via LDS transpose.
__global__ __launch_bounds__(256, 2) void gemm_scores_kernel(
    const float* __restrict__ H, const unsigned short* __restrict__ Wt,
    const float* __restrict__ a, unsigned short* __restrict__ Whb,
    float* __restrict__ s_dst, float* __restrict__ s_src, int N) {
  __shared__ unsigned short Hs[64][264];      // +8 pad
  __shared__ unsigned short Os[4][16][264];   // per-wave store staging
  const int t = threadIdx.x;
  const int r0 = blockIdx.x * 64;
  // stage H tile (fp32 -> bf16), 16 float4 per thread
#pragma unroll
  for (int i = 0; i < 16; ++i) {
    int idx = t + i * 256;  // 4096 float4 chunks; 64 per row
    int row = idx >> 6;
    int c4 = idx & 63;
    int r = r0 + row;
    float4 h = (r < N) ? *(const float4*)&H[(size_t)r * DIM + c4 * 4]
                       : make_float4(0.f, 0.f, 0.f, 0.f);
    unsigned lo = (unsigned)f2bf(h.x) | ((unsigned)f2bf(h.y) << 16);
    unsigned hi = (unsigned)f2bf(h.z) | ((unsigned)f2bf(h.w) << 16);
    *(uint2*)&Hs[row][c4 * 4] = make_uint2(lo, hi);
  }
  __syncthreads();
  const int wave = t >> 6, lane = t & 63;
  const int q = lane >> 4, m = lane & 15;
  const int rowbase = wave * 16;
  // A frags: A[m=lane&15][k=q*8+j] within each 32-wide k-tile
  short8 Af[8];
#pragma unroll
  for (int k0 = 0; k0 < 8; ++k0)
    Af[k0] = *(const short8*)&Hs[rowbase + m][k0 * 32 + q * 8];
  f32x4 acc[16];
#pragma unroll
  for (int j = 0; j < 16; ++j) acc[j] = (f32x4){0.f, 0.f, 0.f, 0.f};
#pragma unroll
  for (int k0 = 0; k0 < 8; ++k0) {
#pragma unroll
    for (int j = 0; j < 16; ++j) {  // B[k][n]: n=m, k=k0*32+q*8+j -> Wt row n contiguous
      short8 Bf = *(const short8*)&Wt[(size_t)(j * 16 + m) * DIM + k0 * 32 + q * 8];
      acc[j] = __builtin_amdgcn_mfma_f32_16x16x32_bf16(Af[k0], Bf, acc[j], 0, 0, 0);
    }
  }
  // epilogue: scores (fp32) + bf16 tile to LDS
  float pd[4] = {0, 0, 0, 0}, ps[4] = {0, 0, 0, 0};
#pragma unroll
  for (int j = 0; j < 16; ++j) {
    int col = j * 16 + m;
    float ad = a[col], as = a[DIM + col];
#pragma unroll
    for (int reg = 0; reg < 4; ++reg) {
      float v = acc[j][reg];  // row = q*4+reg, col
      pd[reg] += v * ad;
      ps[reg] += v * as;
      Os[wave][q * 4 + reg][col] = f2bf(v);
    }
  }
#pragma unroll
  for (int off = 8; off >= 1; off >>= 1) {
#pragma unroll
    for (int reg = 0; reg < 4; ++reg) {
      pd[reg] += __shfl_down(pd[reg], off);
      ps[reg] += __shfl_down(ps[reg], off);
    }
  }
  if (m == 0) {
#pragma unroll
    for (int reg = 0; reg < 4; ++reg) {
      int r = r0 + rowbase + q * 4 + reg;
      if (r < N) {
        s_dst[r] = pd[reg];
        s_src[r] = ps[reg];
      }
    }
  }
  __syncthreads();
  // coalesced bf16 store: wave writes its 16 rows, 8 B/lane (512 B/row)
#pragma unroll
  for (int row = 0; row < 16; ++row) {
    int r = r0 + rowbase + row;
    if (r < N)
      *(uint2*)&Whb[(size_t)r * DIM + lane * 4] = *(const uint2*)&Os[wave][row][lane * 4];
  }
}

// --- CSR build, all 3 types in one pass (blockIdx.y = type) ---
__global__ void csr_count_kernel(const int* __restrict__ r0, const int* __restrict__ r1,
                                 const int* __restrict__ r2, int* __restrict__ counts, int E,
                                 int N) {
  int e = blockIdx.x * blockDim.x + threadIdx.x;
  if (e >= E) return;
  const int* rr = blockIdx.y == 0 ? r0 : (blockIdx.y == 1 ? r1 : r2);
  atomicAdd(&counts[blockIdx.y * N + rr[e]], 1);
}

// grid = 3 blocks x 1024 thr; counts becomes cursor in-place
__global__ void csr_scan_kernel(int* counts, int* row_ptr, int N) {
  __shared__ int part[1024];
  int* cnt = counts + blockIdx.x * N;
  int* rp = row_ptr + blockIdx.x * (N + 1);
  const int t = threadIdx.x;
  const int chunk = (N + 1023) / 1024;
  const int lo = t * chunk;
  const int hi = min(lo + chunk, N);
  int s = 0;
  for (int i = lo; i < hi; ++i) s += cnt[i];
  part[t] = s;
  __syncthreads();
  for (int off = 1; off < 1024; off <<= 1) {
    int u = (t >= off) ? part[t - off] : 0;
    __syncthreads();
    part[t] += u;
    __syncthreads();
  }
  int running = part[t] - s;
  for (int i = lo; i < hi; ++i) {
    int c = cnt[i];       // read BEFORE overwrite (counts aliases cursor)
    rp[i] = running;
    cnt[i] = running;     // cursor init
    running += c;
  }
  if (t == 1023) rp[N] = part[1023];
}

__global__ void csr_scatter_kernel(const int* __restrict__ r0, const int* __restrict__ r1,
                                   const int* __restrict__ r2, const int* __restrict__ c0,
                                   const int* __restrict__ c1, const int* __restrict__ c2,
                                   int* __restrict__ cursor, int* __restrict__ col_csr, int E,
                                   int N) {
  int e = blockIdx.x * blockDim.x + threadIdx.x;
  if (e >= E) return;
  int ty = blockIdx.y;
  const int* rr = ty == 0 ? r0 : (ty == 1 ? r1 : r2);
  const int* cc = ty == 0 ? c0 : (ty == 1 ? c1 : c2);
  int pos = atomicAdd(&cursor[ty * N + rr[e]], 1);
  col_csr[(size_t)ty * E + pos] = cc[e];
}

// one wave per destination node: fused segment-max + softmax aggregation, bf16 gather.
// first=1: out = bias + agg (no read); else: out += agg.
__global__ void gat_node_kernel(const int* __restrict__ row_ptr, const int* __restrict__ col_csr,
                                const float* __restrict__ s_dst, const float* __restrict__ s_src,
                                const unsigned short* __restrict__ Whb,
                                const float* __restrict__ bias, float* __restrict__ out, int N,
                                int first) {
  int n = (int)((blockIdx.x * (unsigned)blockDim.x + threadIdx.x) >> 6);
  if (n >= N) return;
  int lane = threadIdx.x & 63;
  int beg = row_ptr[n], end = row_ptr[n + 1];
  if (!first && beg == end) return;
  float sd = s_dst[n];
  float mx = -__builtin_inff();
  for (int p = beg + lane; p < end; p += 64) {
    float v = sd + s_src[col_csr[p]];
    v = v > 0.f ? v : SLOPE * v;
    mx = fmaxf(mx, v);
  }
#pragma unroll
  for (int off = 32; off >= 1; off >>= 1) mx = fmaxf(mx, __shfl_down(mx, off));
  mx = __shfl(mx, 0);
  float4 acc = {0.f, 0.f, 0.f, 0.f};
  float sum = 0.f;
  for (int p = beg; p < end; ++p) {
    int c = col_csr[p];
    float v = sd + s_src[c];
    v = v > 0.f ? v : SLOPE * v;
    float pe = __expf(v - mx);
    sum += pe;
    ushort4 w = *(const ushort4*)&Whb[(size_t)c * DIM + lane * 4];  // 8 B/lane, 512 B/row
    acc.x += pe * bf2f(w.x);
    acc.y += pe * bf2f(w.y);
    acc.z += pe * bf2f(w.z);
    acc.w += pe * bf2f(w.w);
  }
  float inv = 1.f / fmaxf(sum, 1e-12f);
  float4* o = (float4*)(out + (size_t)n * DIM) + lane;
  float4 cur = first ? ((const float4*)bias)[lane] : *o;
  cur.x += acc.x * inv;
  cur.y += acc.y * inv;
  cur.z += acc.z * inv;
  cur.w += acc.w * inv;
  *o = cur;
}

static inline size_t align256(size_t x) { return (x + 255) & ~(size_t)255; }

extern "C" void kernel_launch(void* const* d_in, const int* in_sizes, int n_in,
                              void* d_out, int out_size, void* d_ws, size_t ws_size,
                              hipStream_t stream) {
  const float* H = (const float*)d_in[0];
  const float* W[3] = {(const float*)d_in[1], (const float*)d_in[2], (const float*)d_in[3]};
  const float* a[3] = {(const float*)d_in[4], (const float*)d_in[5], (const float*)d_in[6]};
  const float* bias = (const float*)d_in[7];
  const int* row[3] = {(const int*)d_in[8], (const int*)d_in[10], (const int*)d_in[12]};
  const int* col[3] = {(const int*)d_in[9], (const int*)d_in[11], (const int*)d_in[13]};
  const int N = in_sizes[0] / DIM;
  const int E = in_sizes[8];
  float* out = (float*)d_out;

  // workspace (~93 MB)
  char* ws = (char*)d_ws;
  size_t off = 0;
  unsigned short* Whb = (unsigned short*)(ws + off);
  off = align256(off + (size_t)N * DIM * sizeof(unsigned short));
  unsigned short* Wt = (unsigned short*)(ws + off);
  off = align256(off + (size_t)3 * DIM * DIM * sizeof(unsigned short));
  float* s_dst = (float*)(ws + off);
  off = align256(off + (size_t)N * sizeof(float));
  float* s_src = (float*)(ws + off);
  off = align256(off + (size_t)N * sizeof(float));
  int* counts = (int*)(ws + off);  // becomes cursor after scan
  off = align256(off + (size_t)3 * N * sizeof(int));
  int* row_ptr = (int*)(ws + off);
  off = align256(off + (size_t)3 * (N + 1) * sizeof(int));
  int* col_csr = (int*)(ws + off);
  off = align256(off + (size_t)3 * E * sizeof(int));

  const int eblocks = (E + 255) / 256;
  // weight transpose + CSR build (all types, independent of GEMM)
  wtrans_kernel<<<dim3(DIM, 3), 256, 0, stream>>>(W[0], W[1], W[2], Wt);
  hipMemsetAsync(counts, 0, (size_t)3 * N * sizeof(int), stream);
  csr_count_kernel<<<dim3(eblocks, 3), 256, 0, stream>>>(row[0], row[1], row[2], counts, E, N);
  csr_scan_kernel<<<3, 1024, 0, stream>>>(counts, row_ptr, N);
  csr_scatter_kernel<<<dim3(eblocks, 3), 256, 0, stream>>>(row[0], row[1], row[2], col[0], col[1],
                                                           col[2], counts, col_csr, E, N);

  for (int t = 0; t < 3; ++t) {
    gemm_scores_kernel<<<(N + 63) / 64, 256, 0, stream>>>(H, Wt + (size_t)t * DIM * DIM, a[t],
                                                          Whb, s_dst, s_src, N);
    gat_node_kernel<<<(N * 64 + 255) / 256, 256, 0, stream>>>(
        row_ptr + (size_t)t * (N + 1), col_csr + (size_t)t * E, s_dst, s_src, Whb, bias, out, N,
        t == 0 ? 1 : 0);
  }
  (void)n_in;
  (void)out_size;
  (void)ws_size;
}